// Round 13
// baseline (143.072 us; speedup 1.0000x reference)
//
#include <hip/hip_runtime.h>
#include <math.h>

#define N_IMG 8
#define N_ANCH 250000
#define PRE_K 2000
#define POST_K 1000
#define SORT_N 2048
#define CAND_CAP 8192  // >= G + boundary-bin count (expected ~5.7K, ~39 sigma margin)
#define NMS_WORDS 32   // ceil(2000/64)
#define NPAIR 16       // pairs of 64-row chunks
#define CNT_STRIDE 64  // uints per image: 256B -> private cacheline per image

#define IMG_W_M1 1332.0f
#define IMG_H_M1 799.0f
#define DCLIP 4.135166556742356f
#define NMS_T 0.7f

__device__ __forceinline__ float rn_add(float a, float b){ return __fadd_rn(a,b); }
__device__ __forceinline__ float rn_sub(float a, float b){ return __fsub_rn(a,b); }
__device__ __forceinline__ float rn_mul(float a, float b){ return __fmul_rn(a,b); }
__device__ __forceinline__ float rn_div(float a, float b){ return __fdiv_rn(a,b); }

// monotonic float->uint mapping (order-preserving, larger float -> larger uint)
__device__ __forceinline__ unsigned int mono_of(float f){
  unsigned int u = __float_as_uint(f);
  return u ^ ((u >> 31) ? 0xFFFFFFFFu : 0x80000000u);
}

// exact-op-order IoU > 0.7 test (mirrors reference float32 op sequence;
// fully symmetric in its two boxes: max/min/add/mul commutative)
__device__ __forceinline__ bool iou_gt(float x1,float y1,float x2,float y2,float a1,
                                       float X1,float Y1,float X2,float Y2,float a2){
  float ltx = fmaxf(x1, X1), lty = fmaxf(y1, Y1);
  float rbx = fminf(x2, X2), rby = fminf(y2, Y2);
  float wx = fmaxf(rn_add(rn_sub(rbx, ltx), 1.0f), 0.0f);
  float wy = fmaxf(rn_add(rn_sub(rby, lty), 1.0f), 0.0f);
  float inter = rn_mul(wx, wy);
  float iou = rn_div(inter, rn_sub(rn_add(a1, a2), inter));
  return iou > NMS_T;
}

// ---------------- histogram, PRIVATIZED: per-block slice, no atomics/init ----------------
__global__ void k_hist(const float* __restrict__ obj, unsigned int* __restrict__ hsl){
  __shared__ unsigned int lh[2048];
  int img = blockIdx.y;
  for (int i = threadIdx.x; i < 2048; i += blockDim.x) lh[i] = 0;
  __syncthreads();
  const float4* o4 = (const float4*)(obj + (size_t)img * N_ANCH);
  int stride = gridDim.x * blockDim.x;
  for (int i = blockIdx.x * blockDim.x + threadIdx.x; i < N_ANCH/4; i += stride){
    float4 v = o4[i];
    atomicAdd(&lh[mono_of(v.x) >> 21], 1u);
    atomicAdd(&lh[mono_of(v.y) >> 21], 1u);
    atomicAdd(&lh[mono_of(v.z) >> 21], 1u);
    atomicAdd(&lh[mono_of(v.w) >> 21], 1u);
  }
  __syncthreads();
  unsigned int* slice = hsl + ((size_t)img * 64 + blockIdx.x) * 2048;
  for (int i = threadIdx.x; i < 2048; i += blockDim.x) slice[i] = lh[i];
}

// ---------------- sum slices + parallel suffix scan -> boundary bin; zero cnt ----------------
__global__ void __launch_bounds__(1024) k_scan(const unsigned int* __restrict__ hsl,
                                               unsigned int* state, unsigned int* cnt){
  __shared__ unsigned int bins[2048];
  __shared__ unsigned int gtot[16];
  __shared__ unsigned int Gsuf[17];
  __shared__ unsigned int res;
  int img = blockIdx.x, tid = threadIdx.x;
  int wv = tid >> 6, lane = tid & 63;
  #pragma unroll
  for (int h = 0; h < 2; ++h){
    int bin = tid + h*1024;
    unsigned int acc = 0;
    #pragma unroll 8
    for (int s = 0; s < 64; ++s) acc += hsl[((size_t)img*64 + s)*2048 + bin];
    bins[bin] = acc;
  }
  __syncthreads();
  {
    unsigned int x0 = bins[wv*128 + lane];
    unsigned int x1 = bins[wv*128 + 64 + lane];
    unsigned int s1 = x1, s0 = x0, v;
    #pragma unroll
    for (int off = 1; off < 64; off <<= 1){
      v = __shfl_down(s1, off, 64); if (lane + off < 64) s1 += v;
      v = __shfl_down(s0, off, 64); if (lane + off < 64) s0 += v;
    }
    unsigned int T1 = __shfl(s1, 0, 64);
    s0 += T1;
    bins[wv*128 + lane] = s0;
    bins[wv*128 + 64 + lane] = s1;
    if (lane == 0) gtot[wv] = s0;
  }
  __syncthreads();
  if (tid < 64){
    unsigned int x = (tid < 16) ? gtot[tid] : 0u;
    #pragma unroll
    for (int off = 1; off < 16; off <<= 1){
      unsigned int v = __shfl_down(x, off, 64);
      if (tid + off < 16) x += v;
    }
    if (tid < 16) Gsuf[tid] = x;
    if (tid == 16) Gsuf[16] = 0u;
  }
  __syncthreads();
  #pragma unroll
  for (int h = 0; h < 2; ++h){
    int d = tid + h*1024;
    unsigned int Sd  = bins[d] + Gsuf[(d >> 7) + 1];
    unsigned int Sd1 = (d < 2047) ? (bins[d+1] + Gsuf[((d+1) >> 7) + 1]) : 0u;
    if (Sd >= PRE_K && Sd1 < PRE_K) res = (unsigned int)d;
  }
  __syncthreads();
  if (tid == 0) state[img] = res;
  if (tid < CNT_STRIDE) cnt[img*CNT_STRIDE + tid] = 0;
}

// ---------------- collect candidates: top-11 bits >= boundary bin ----------------
__global__ void k_cand(const float* __restrict__ obj, const unsigned int* __restrict__ state,
                       unsigned int* cnt, unsigned long long* __restrict__ cand){
  int img = blockIdx.y;
  unsigned int bin = state[img];
  const float4* o4 = (const float4*)(obj + (size_t)img * N_ANCH);
  int stride = gridDim.x * blockDim.x;
  int lane = threadIdx.x & 63;
  unsigned long long below = (lane == 0) ? 0ull : ((~0ull) >> (64 - lane));
  for (int i = blockIdx.x * blockDim.x + threadIdx.x; i < N_ANCH/4; i += stride){
    float4 v = o4[i];
    #pragma unroll
    for (int s = 0; s < 4; ++s){
      float f = (s==0) ? v.x : (s==1) ? v.y : (s==2) ? v.z : v.w;
      unsigned int key = mono_of(f);
      bool hit = (key >> 21) >= bin;
      unsigned long long b = __ballot(hit);
      if (b){
        int leader = (int)(__ffsll((long long)b) - 1);
        unsigned int base = 0;
        if (lane == leader) base = atomicAdd(&cnt[img*CNT_STRIDE], (unsigned int)__popcll(b));
        base = (unsigned int)__shfl((int)base, leader, 64);
        if (hit){
          unsigned int slot = base + (unsigned int)__popcll(b & below);
          if (slot < CAND_CAP)
            cand[(size_t)img*CAND_CAP + slot] =
              ((unsigned long long)key << 32) | (unsigned long long)(~(unsigned int)(i*4 + s));
        }
      }
    }
  }
}

// ---------------- per-image: exact radix select + tie rule + sort + decode ----------------
// Round-12 profile (50us, 34.6K bank conflicts, 2.2MB FETCH): candidates were
// re-read from global 4x; bitonic strides hit LDS bank aliasing; scatter did
// ~2000 serial same-address LDS atomics. Fixes: LDS candidate cache (load
// once), SP(i)=i+(i>>4) padded sort array, wave-aggregated scatter.
#define SP(i) ((i) + ((i) >> 4))
__global__ void __launch_bounds__(1024) k_selsort(
    const unsigned long long* __restrict__ cand, const unsigned int* __restrict__ cnt,
    const float* __restrict__ anchors, const float* __restrict__ deltas,
    float* __restrict__ boxes, float* __restrict__ scores,
    float* __restrict__ areas, unsigned int* __restrict__ valid){
  __shared__ unsigned long long cl[CAND_CAP];             // 64 KB candidate cache
  __shared__ unsigned long long sel_l[SORT_N + (SORT_N >> 4)];  // 17 KB padded
  __shared__ unsigned int bins[2048];                     // 8 KB
  __shared__ unsigned int scal[4];                        // rem, bin, cgt, ceq
  __shared__ unsigned int gtot[16];
  __shared__ unsigned int Gsuf[17];
  int img = blockIdx.x, tid = threadIdx.x;
  int wv = tid >> 6, lane = tid & 63;
  unsigned int n = cnt[img*CNT_STRIDE]; if (n > CAND_CAP) n = CAND_CAP;
  const unsigned long long* cd = cand + (size_t)img*CAND_CAP;

  // load candidates ONCE (coalesced); all passes hit LDS afterwards
  for (unsigned int i = tid; i < n; i += 1024) cl[i] = cd[i];

  unsigned int rem = PRE_K, prefix = 0;
  #pragma unroll
  for (int p = 0; p < 3; ++p){
    int shift  = (p==0) ? 21 : (p==1) ? 10 : 0;
    int mshift = (p==0) ? 32 : (p==1) ? 21 : 10;
    unsigned int bmask = (p==2) ? 1023u : 2047u;
    bins[tid] = 0; bins[tid+1024] = 0;
    __syncthreads();
    for (unsigned int i = tid; i < n; i += 1024){
      unsigned int k32 = (unsigned int)(cl[i] >> 32);
      bool m = (mshift >= 32) || ((k32 >> mshift) == (prefix >> mshift));
      if (m) atomicAdd(&bins[(k32 >> shift) & bmask], 1u);
    }
    __syncthreads();
    {
      unsigned int x0 = bins[wv*128 + lane];
      unsigned int x1 = bins[wv*128 + 64 + lane];
      unsigned int s1 = x1, s0 = x0, v;
      #pragma unroll
      for (int off = 1; off < 64; off <<= 1){
        v = __shfl_down(s1, off, 64); if (lane + off < 64) s1 += v;
        v = __shfl_down(s0, off, 64); if (lane + off < 64) s0 += v;
      }
      unsigned int T1 = __shfl(s1, 0, 64);
      s0 += T1;
      bins[wv*128 + lane] = s0;
      bins[wv*128 + 64 + lane] = s1;
      if (lane == 0) gtot[wv] = s0;
    }
    __syncthreads();
    if (tid < 64){
      unsigned int x = (tid < 16) ? gtot[tid] : 0u;
      #pragma unroll
      for (int off = 1; off < 16; off <<= 1){
        unsigned int v = __shfl_down(x, off, 64);
        if (tid + off < 16) x += v;
      }
      if (tid < 16) Gsuf[tid] = x;
      if (tid == 16) Gsuf[16] = 0u;
    }
    __syncthreads();
    #pragma unroll
    for (int h = 0; h < 2; ++h){
      int d = tid + h*1024;
      unsigned int Sd  = bins[d] + Gsuf[(d >> 7) + 1];
      unsigned int Sd1 = (d < 2047) ? (bins[d+1] + Gsuf[((d+1) >> 7) + 1]) : 0u;
      if (Sd >= rem && Sd1 < rem){ scal[0] = rem - Sd1; scal[1] = (unsigned int)d; }
    }
    __syncthreads();
    rem = scal[0]; prefix |= scal[1] << shift;
    __syncthreads();
  }
  unsigned int T = prefix;
  unsigned int G = PRE_K - rem;   // # strictly greater than T; rem ties needed
  if (tid == 0){ scal[2] = 0; scal[3] = 0; }
  __syncthreads();
  // wave-aggregated scatter (slot order arbitrary; sort fixes final order)
  {
    unsigned long long below = (lane == 0) ? 0ull : ((~0ull) >> (64 - lane));
    for (unsigned int i = tid; i < n; i += 1024){
      unsigned long long pk = cl[i];
      unsigned int k32 = (unsigned int)(pk >> 32);
      bool gt = k32 > T, eq = k32 == T;
      unsigned long long bgt = __ballot(gt);
      if (bgt){
        int leader = (int)(__ffsll((long long)bgt) - 1);
        unsigned int base = 0;
        if (lane == leader) base = atomicAdd(&scal[2], (unsigned int)__popcll(bgt));
        base = (unsigned int)__shfl((int)base, leader, 64);
        if (gt){
          unsigned int s = base + (unsigned int)__popcll(bgt & below);  // s < G
          sel_l[SP(s)] = pk;
        }
      }
      unsigned long long beq = __ballot(eq);
      if (beq){
        int leader = (int)(__ffsll((long long)beq) - 1);
        unsigned int base = 0;
        if (lane == leader) base = atomicAdd(&scal[3], (unsigned int)__popcll(beq));
        base = (unsigned int)__shfl((int)base, leader, 64);
        if (eq){
          unsigned int e = base + (unsigned int)__popcll(beq & below);
          if (G + e < SORT_N) sel_l[SP(G + e)] = pk;
        }
      }
    }
  }
  __syncthreads();
  unsigned int ceq = scal[3];
  unsigned int tcap = SORT_N - G;
  unsigned int filled = G + ((ceq < tcap) ? ceq : tcap);
  for (unsigned int i = filled + tid; i < SORT_N; i += 1024) sel_l[SP(i)] = 0ull;
  __syncthreads();
  // bitonic sort 2048 descending: (key desc, idx asc) via ~idx packing
  for (int k = 2; k <= SORT_N; k <<= 1){
    for (int j = k >> 1; j > 0; j >>= 1){
      for (int i = tid; i < SORT_N; i += 1024){
        int ixj = i ^ j;
        if (ixj > i){
          bool up = ((i & k) == 0);
          unsigned long long x = sel_l[SP(i)], y = sel_l[SP(ixj)];
          if ((x < y) == up){ sel_l[SP(i)] = y; sel_l[SP(ixj)] = x; }
        }
      }
      __syncthreads();
    }
  }
  // decode + clip the exact top-2000 (score rebuilt bit-exactly from key)
  for (int k = tid; k < PRE_K; k += 1024){
    unsigned long long pk = sel_l[SP(k)];
    unsigned int key = (unsigned int)(pk >> 32);
    unsigned int idx = ~(unsigned int)(pk & 0xFFFFFFFFull);
    unsigned int ub = (key & 0x80000000u) ? (key ^ 0x80000000u) : (key ^ 0xFFFFFFFFu);
    float sc = __uint_as_float(ub);
    float4 a = ((const float4*)anchors)[idx];
    float4 d = ((const float4*)deltas)[(size_t)img*N_ANCH + idx];
    float w  = rn_add(rn_sub(a.z, a.x), 1.0f);
    float h  = rn_add(rn_sub(a.w, a.y), 1.0f);
    float cx = rn_add(a.x, rn_mul(0.5f, w));
    float cy = rn_add(a.y, rn_mul(0.5f, h));
    float dw = fminf(d.z, DCLIP);
    float dh = fminf(d.w, DCLIP);
    float pcx = rn_add(rn_mul(d.x, w), cx);
    float pcy = rn_add(rn_mul(d.y, h), cy);
    float pw = rn_mul((float)exp((double)dw), w);   // correctly-rounded f32 exp
    float ph = rn_mul((float)exp((double)dh), h);
    float x1 = rn_sub(pcx, rn_mul(0.5f, pw));
    float y1 = rn_sub(pcy, rn_mul(0.5f, ph));
    float x2 = rn_sub(rn_add(pcx, rn_mul(0.5f, pw)), 1.0f);
    float y2 = rn_sub(rn_add(pcy, rn_mul(0.5f, ph)), 1.0f);
    x1 = fminf(fmaxf(x1, 0.0f), IMG_W_M1);
    x2 = fminf(fmaxf(x2, 0.0f), IMG_W_M1);
    y1 = fminf(fmaxf(y1, 0.0f), IMG_H_M1);
    y2 = fminf(fmaxf(y2, 0.0f), IMG_H_M1);
    float bw = rn_add(rn_sub(x2, x1), 1.0f);
    float bh = rn_add(rn_sub(y2, y1), 1.0f);
    ((float4*)boxes)[(size_t)img*PRE_K + k] = make_float4(x1, y1, x2, y2);
    scores[img*PRE_K + k] = sc;
    areas[img*PRE_K + k]  = rn_mul(bw, bh);
    valid[img*PRE_K + k]  = (bw >= 0.0f && bh >= 0.0f) ? 1u : 0u;
  }
}

// ---------------- NMS suppression bitmask, BLOCK-TRANSPOSED: mtt[w][r][l] ----------------
// bit b of mtt[w][r][l] = "row r*64+b suppresses column w*64+l" (row < col).
__global__ void k_mask(const float* __restrict__ boxes, const float* __restrict__ areas,
                       unsigned long long* __restrict__ mtt){
  int w = blockIdx.x, r = blockIdx.y, img = blockIdx.z;
  if (w < r) return;
  __shared__ float4 rb[64];
  __shared__ float  ra[64];
  int ri = r*64 + threadIdx.x;
  if (ri < PRE_K){
    rb[threadIdx.x] = ((const float4*)boxes)[(size_t)img*PRE_K + ri];
    ra[threadIdx.x] = areas[img*PRE_K + ri];
  }
  __syncthreads();
  int j = w*64 + threadIdx.x;   // this thread's column
  unsigned long long bits = 0;
  if (j < PRE_K){
    float4 bj = ((const float4*)boxes)[(size_t)img*PRE_K + j];
    float aj = areas[img*PRE_K + j];
    int bmax = min(64, PRE_K - r*64);
    for (int b = 0; b < bmax; ++b){
      int row = r*64 + b;
      if (row >= j) continue;
      float4 br = rb[b];
      if (iou_gt(br.x,br.y,br.z,br.w,ra[b], bj.x,bj.y,bj.z,bj.w,aj)) bits |= 1ull << b;
    }
  }
  mtt[(size_t)img*(NMS_WORDS*NMS_WORDS*64) + ((size_t)w*NMS_WORDS + r)*64 + threadIdx.x] = bits;
}

// ---------------- greedy NMS reduce: Jacobi-fixpoint resolve + raw barriers ----------------
__global__ void __launch_bounds__(1024) k_nms_out(const unsigned long long* __restrict__ mtt,
                          const unsigned int* __restrict__ valid,
                          const float* __restrict__ boxes, const float* __restrict__ scores,
                          float* __restrict__ out){
  __shared__ unsigned long long keepw[NMS_WORDS];
  __shared__ unsigned int kpre[NMS_WORDS + 1];
  int img = blockIdx.x;
  int tid = threadIdx.x;
  int wv = tid >> 6, lane = tid & 63;
  const unsigned long long* M = mtt + (size_t)img * (NMS_WORDS * NMS_WORDS * 64);
  int wA = wv*2, wB = wv*2 + 1;

  int rA = wA*64 + lane, rB = wB*64 + lane;
  bool okA = (rA < PRE_K) && (valid[img*PRE_K + rA] != 0u);
  bool okB = (rB < PRE_K) && (valid[img*PRE_K + rB] != 0u);
  unsigned long long vA = __ballot(okA);
  unsigned long long vB = __ballot(okB);

  unsigned long long tdgA = M[((size_t)wA*NMS_WORDS + wA)*64 + lane];
  unsigned long long tdgB = M[((size_t)wB*NMS_WORDS + wB)*64 + lane];
  unsigned long long tX   = M[((size_t)wB*NMS_WORDS + wA)*64 + lane];

  bool deadA = false, deadB = false;

  unsigned long long a0=0, a1=0, b0=0, b1=0, n0=0, n1=0, n2=0, n3=0;
  if (wv > 0){
    a0 = M[((size_t)wA*NMS_WORDS + 0)*64 + lane];
    a1 = M[((size_t)wA*NMS_WORDS + 1)*64 + lane];
    b0 = M[((size_t)wB*NMS_WORDS + 0)*64 + lane];
    b1 = M[((size_t)wB*NMS_WORDS + 1)*64 + lane];
  }
  if (wv > 1){
    n0 = M[((size_t)wA*NMS_WORDS + 2)*64 + lane];
    n1 = M[((size_t)wA*NMS_WORDS + 3)*64 + lane];
    n2 = M[((size_t)wB*NMS_WORDS + 2)*64 + lane];
    n3 = M[((size_t)wB*NMS_WORDS + 3)*64 + lane];
  }

  for (int p = 0; p < NPAIR; ++p){
    if (wv == p){
      unsigned long long base = vA & ~__ballot(deadA);
      unsigned long long alive = base, prev;
      do {
        prev = alive;
        alive = base & ~__ballot((tdgA & prev) != 0ull);
      } while (alive != prev);
      unsigned long long kA = alive;
      unsigned long long supX = __ballot((tX & kA) != 0ull);
      unsigned long long baseB = vB & ~(__ballot(deadB) | supX);
      alive = baseB;
      do {
        prev = alive;
        alive = baseB & ~__ballot((tdgB & prev) != 0ull);
      } while (alive != prev);
      if (lane == 0){ keepw[wA] = kA; keepw[wB] = alive; }
    }
    __builtin_amdgcn_sched_barrier(0);
    asm volatile("s_waitcnt lgkmcnt(0)" ::: "memory");
    __builtin_amdgcn_s_barrier();
    __builtin_amdgcn_sched_barrier(0);
    if (wv > p){
      unsigned long long k0 = keepw[2*p], k1 = keepw[2*p+1];
      deadA = deadA || ((a0 & k0) != 0ull) || ((a1 & k1) != 0ull);
      deadB = deadB || ((b0 & k0) != 0ull) || ((b1 & k1) != 0ull);
      a0 = n0; a1 = n1; b0 = n2; b1 = n3;
      if (wv > p + 2){
        n0 = M[((size_t)wA*NMS_WORDS + (2*p+4))*64 + lane];
        n1 = M[((size_t)wA*NMS_WORDS + (2*p+5))*64 + lane];
        n2 = M[((size_t)wB*NMS_WORDS + (2*p+4))*64 + lane];
        n3 = M[((size_t)wB*NMS_WORDS + (2*p+5))*64 + lane];
      }
    }
  }

  __syncthreads();
  if (tid == 0){
    unsigned int s = 0;
    for (int ww = 0; ww < NMS_WORDS; ++ww){ kpre[ww] = s; s += __popcll(keepw[ww]); }
    kpre[NMS_WORDS] = s;
  }
  __syncthreads();
  unsigned int nkept = kpre[NMS_WORDS];
  for (int i = tid; i < PRE_K; i += blockDim.x){
    int ww = i >> 6, b = i & 63;
    unsigned long long kw = keepw[ww];
    bool kept = (kw >> b) & 1ull;
    unsigned long long below = (b == 0) ? 0ull : (kw & ((~0ull) >> (64 - b)));
    unsigned int rank = kpre[ww] + (unsigned int)__popcll(below);
    unsigned int pos = kept ? rank : (nkept + (unsigned int)i - rank);
    if (pos < POST_K){
      float4 bx = ((const float4*)boxes)[(size_t)img*PRE_K + i];
      float sc = kept ? scores[img*PRE_K + i] : -1e9f;
      float* o = out + ((size_t)img*POST_K + pos) * 5;
      o[0] = bx.x; o[1] = bx.y; o[2] = bx.z; o[3] = bx.w; o[4] = sc;
    }
  }
}

extern "C" void kernel_launch(void* const* d_in, const int* in_sizes, int n_in,
                              void* d_out, int out_size, void* d_ws, size_t ws_size,
                              hipStream_t stream) {
  const float* anchors    = (const float*)d_in[0];
  const float* objectness = (const float*)d_in[1];
  const float* deltas     = (const float*)d_in[2];
  float* out = (float*)d_out;
  char* ws = (char*)d_ws;

  unsigned int* state      = (unsigned int*)(ws + 0);        // 32
  unsigned int* cnt        = (unsigned int*)(ws + 256);      // 2048 (256B/img)
  float* boxes             = (float*)(ws + 4096);            // 256000 (16B aligned)
  float* scores            = (float*)(ws + 260096);          // 64000
  float* areas             = (float*)(ws + 324096);          // 64000
  unsigned int* valid      = (unsigned int*)(ws + 388096);   // 64000
  // one 4 MB region reused sequentially (write->read fully ordered by stream):
  //   hsl  (hist slices, 8*64*2048*4 = 4 MB)   w:k_hist   r:k_scan
  //   cand (8*8192*8 = 512 KB)                 w:k_cand   r:k_selsort
  //   mtt  (block-transposed mask, 4 MB)       w:k_mask   r:k_nms_out
  unsigned int* hsl        = (unsigned int*)(ws + 458752);
  unsigned long long* cand = (unsigned long long*)(ws + 458752);
  unsigned long long* mtt  = (unsigned long long*)(ws + 458752);

  hipLaunchKernelGGL(k_hist, dim3(64, N_IMG), dim3(256), 0, stream, objectness, hsl);
  hipLaunchKernelGGL(k_scan, dim3(N_IMG), dim3(1024), 0, stream, hsl, state, cnt);
  hipLaunchKernelGGL(k_cand, dim3(64, N_IMG), dim3(256), 0, stream,
                     objectness, state, cnt, cand);
  hipLaunchKernelGGL(k_selsort, dim3(N_IMG), dim3(1024), 0, stream,
                     cand, cnt, anchors, deltas, boxes, scores, areas, valid);
  hipLaunchKernelGGL(k_mask, dim3(NMS_WORDS, NMS_WORDS, N_IMG), dim3(64), 0, stream,
                     boxes, areas, mtt);
  hipLaunchKernelGGL(k_nms_out, dim3(N_IMG), dim3(1024), 0, stream,
                     mtt, valid, boxes, scores, out);
}

// Round 14
// 137.329 us; speedup vs baseline: 1.0418x; 1.0418x over previous
//
#include <hip/hip_runtime.h>
#include <math.h>

#define N_IMG 8
#define N_ANCH 250000
#define PRE_K 2000
#define POST_K 1000
#define SORT_N 2048
#define CAND_CAP 8192  // >= G + boundary-bin count (expected ~5.7K, ~39 sigma margin)
#define NMS_WORDS 32   // ceil(2000/64)
#define NPAIR 16       // pairs of 64-row chunks
#define CNT_STRIDE 64  // uints per image: 256B -> private cacheline per image

#define IMG_W_M1 1332.0f
#define IMG_H_M1 799.0f
#define DCLIP 4.135166556742356f
#define NMS_T 0.7f

__device__ __forceinline__ float rn_add(float a, float b){ return __fadd_rn(a,b); }
__device__ __forceinline__ float rn_sub(float a, float b){ return __fsub_rn(a,b); }
__device__ __forceinline__ float rn_mul(float a, float b){ return __fmul_rn(a,b); }
__device__ __forceinline__ float rn_div(float a, float b){ return __fdiv_rn(a,b); }

// monotonic float->uint mapping (order-preserving, larger float -> larger uint)
__device__ __forceinline__ unsigned int mono_of(float f){
  unsigned int u = __float_as_uint(f);
  return u ^ ((u >> 31) ? 0xFFFFFFFFu : 0x80000000u);
}

// exact-op-order IoU > 0.7 test (mirrors reference float32 op sequence;
// fully symmetric in its two boxes: max/min/add/mul commutative)
__device__ __forceinline__ bool iou_gt(float x1,float y1,float x2,float y2,float a1,
                                       float X1,float Y1,float X2,float Y2,float a2){
  float ltx = fmaxf(x1, X1), lty = fmaxf(y1, Y1);
  float rbx = fminf(x2, X2), rby = fminf(y2, Y2);
  float wx = fmaxf(rn_add(rn_sub(rbx, ltx), 1.0f), 0.0f);
  float wy = fmaxf(rn_add(rn_sub(rby, lty), 1.0f), 0.0f);
  float inter = rn_mul(wx, wy);
  float iou = rn_div(inter, rn_sub(rn_add(a1, a2), inter));
  return iou > NMS_T;
}

// ---------------- histogram, PRIVATIZED: per-block slice, no atomics/init ----------------
__global__ void k_hist(const float* __restrict__ obj, unsigned int* __restrict__ hsl){
  __shared__ unsigned int lh[2048];
  int img = blockIdx.y;
  for (int i = threadIdx.x; i < 2048; i += blockDim.x) lh[i] = 0;
  __syncthreads();
  const float4* o4 = (const float4*)(obj + (size_t)img * N_ANCH);
  int stride = gridDim.x * blockDim.x;
  for (int i = blockIdx.x * blockDim.x + threadIdx.x; i < N_ANCH/4; i += stride){
    float4 v = o4[i];
    atomicAdd(&lh[mono_of(v.x) >> 21], 1u);
    atomicAdd(&lh[mono_of(v.y) >> 21], 1u);
    atomicAdd(&lh[mono_of(v.z) >> 21], 1u);
    atomicAdd(&lh[mono_of(v.w) >> 21], 1u);
  }
  __syncthreads();
  unsigned int* slice = hsl + ((size_t)img * 64 + blockIdx.x) * 2048;
  for (int i = threadIdx.x; i < 2048; i += blockDim.x) slice[i] = lh[i];
}

// ------- sum slices + suffix scan -> boundary bin AND rem0 (pass-0 result); zero cnt -------
// Round-13 lesson: k_selsort's radix pass 0 over candidates funnels ~5.7K
// same-address LDS atomics (all candidates share top-11 bits) -> ~48K
// serialization cycles. But pass 0's (bin, rem) is fully determined by THIS
// kernel's histogram -- emit both and skip pass 0 downstream.
__global__ void __launch_bounds__(1024) k_scan(const unsigned int* __restrict__ hsl,
                                               unsigned int* state, unsigned int* cnt){
  __shared__ unsigned int bins[2048];
  __shared__ unsigned int gtot[16];
  __shared__ unsigned int Gsuf[17];
  __shared__ unsigned int res[2];
  int img = blockIdx.x, tid = threadIdx.x;
  int wv = tid >> 6, lane = tid & 63;
  #pragma unroll
  for (int h = 0; h < 2; ++h){
    int bin = tid + h*1024;
    unsigned int acc = 0;
    #pragma unroll 8
    for (int s = 0; s < 64; ++s) acc += hsl[((size_t)img*64 + s)*2048 + bin];
    bins[bin] = acc;
  }
  __syncthreads();
  {
    unsigned int x0 = bins[wv*128 + lane];
    unsigned int x1 = bins[wv*128 + 64 + lane];
    unsigned int s1 = x1, s0 = x0, v;
    #pragma unroll
    for (int off = 1; off < 64; off <<= 1){
      v = __shfl_down(s1, off, 64); if (lane + off < 64) s1 += v;
      v = __shfl_down(s0, off, 64); if (lane + off < 64) s0 += v;
    }
    unsigned int T1 = __shfl(s1, 0, 64);
    s0 += T1;
    bins[wv*128 + lane] = s0;
    bins[wv*128 + 64 + lane] = s1;
    if (lane == 0) gtot[wv] = s0;
  }
  __syncthreads();
  if (tid < 64){
    unsigned int x = (tid < 16) ? gtot[tid] : 0u;
    #pragma unroll
    for (int off = 1; off < 16; off <<= 1){
      unsigned int v = __shfl_down(x, off, 64);
      if (tid + off < 16) x += v;
    }
    if (tid < 16) Gsuf[tid] = x;
    if (tid == 16) Gsuf[16] = 0u;
  }
  __syncthreads();
  #pragma unroll
  for (int h = 0; h < 2; ++h){
    int d = tid + h*1024;
    unsigned int Sd  = bins[d] + Gsuf[(d >> 7) + 1];
    unsigned int Sd1 = (d < 2047) ? (bins[d+1] + Gsuf[((d+1) >> 7) + 1]) : 0u;
    if (Sd >= PRE_K && Sd1 < PRE_K){ res[0] = (unsigned int)d; res[1] = PRE_K - Sd1; }
  }
  __syncthreads();
  if (tid == 0){ state[img] = res[0]; state[8 + img] = res[1]; }
  if (tid < CNT_STRIDE) cnt[img*CNT_STRIDE + tid] = 0;
}

// ---------------- collect candidates: top-11 bits >= boundary bin ----------------
__global__ void k_cand(const float* __restrict__ obj, const unsigned int* __restrict__ state,
                       unsigned int* cnt, unsigned long long* __restrict__ cand){
  int img = blockIdx.y;
  unsigned int bin = state[img];
  const float4* o4 = (const float4*)(obj + (size_t)img * N_ANCH);
  int stride = gridDim.x * blockDim.x;
  int lane = threadIdx.x & 63;
  unsigned long long below = (lane == 0) ? 0ull : ((~0ull) >> (64 - lane));
  for (int i = blockIdx.x * blockDim.x + threadIdx.x; i < N_ANCH/4; i += stride){
    float4 v = o4[i];
    #pragma unroll
    for (int s = 0; s < 4; ++s){
      float f = (s==0) ? v.x : (s==1) ? v.y : (s==2) ? v.z : v.w;
      unsigned int key = mono_of(f);
      bool hit = (key >> 21) >= bin;
      unsigned long long b = __ballot(hit);
      if (b){
        int leader = (int)(__ffsll((long long)b) - 1);
        unsigned int base = 0;
        if (lane == leader) base = atomicAdd(&cnt[img*CNT_STRIDE], (unsigned int)__popcll(b));
        base = (unsigned int)__shfl((int)base, leader, 64);
        if (hit){
          unsigned int slot = base + (unsigned int)__popcll(b & below);
          if (slot < CAND_CAP)
            cand[(size_t)img*CAND_CAP + slot] =
              ((unsigned long long)key << 32) | (unsigned long long)(~(unsigned int)(i*4 + s));
        }
      }
    }
  }
}

// ---------------- per-image: radix passes 1-2 + tie rule + sort + decode ----------------
// Pass 0 eliminated (k_scan supplies bin+rem). cl[] LDS cache and SP padding
// reverted (round-13 falsified both: cand is L2-resident; bitonic operands
// are lane-consecutive -> inherently conflict-free).
__global__ void __launch_bounds__(1024) k_selsort(
    const unsigned long long* __restrict__ cand, const unsigned int* __restrict__ cnt,
    const unsigned int* __restrict__ state,
    const float* __restrict__ anchors, const float* __restrict__ deltas,
    float* __restrict__ boxes, float* __restrict__ scores,
    float* __restrict__ areas, unsigned int* __restrict__ valid){
  __shared__ unsigned long long sel_l[SORT_N];  // 16 KB
  __shared__ unsigned int bins[2048];           // 8 KB
  __shared__ unsigned int scal[4];              // rem, bin, cgt, ceq
  __shared__ unsigned int gtot[16];
  __shared__ unsigned int Gsuf[17];
  int img = blockIdx.x, tid = threadIdx.x;
  int wv = tid >> 6, lane = tid & 63;
  unsigned int n = cnt[img*CNT_STRIDE]; if (n > CAND_CAP) n = CAND_CAP;
  const unsigned long long* cd = cand + (size_t)img*CAND_CAP;

  unsigned int rem = state[8 + img];
  unsigned int prefix = state[img] << 21;
  #pragma unroll
  for (int p = 1; p < 3; ++p){
    int shift  = (p==1) ? 10 : 0;
    int mshift = (p==1) ? 21 : 10;
    unsigned int bmask = (p==2) ? 1023u : 2047u;
    bins[tid] = 0; bins[tid+1024] = 0;
    __syncthreads();
    for (unsigned int i = tid; i < n; i += 1024){
      unsigned int k32 = (unsigned int)(cd[i] >> 32);
      if ((k32 >> mshift) == (prefix >> mshift))
        atomicAdd(&bins[(k32 >> shift) & bmask], 1u);
    }
    __syncthreads();
    {
      unsigned int x0 = bins[wv*128 + lane];
      unsigned int x1 = bins[wv*128 + 64 + lane];
      unsigned int s1 = x1, s0 = x0, v;
      #pragma unroll
      for (int off = 1; off < 64; off <<= 1){
        v = __shfl_down(s1, off, 64); if (lane + off < 64) s1 += v;
        v = __shfl_down(s0, off, 64); if (lane + off < 64) s0 += v;
      }
      unsigned int T1 = __shfl(s1, 0, 64);
      s0 += T1;
      bins[wv*128 + lane] = s0;
      bins[wv*128 + 64 + lane] = s1;
      if (lane == 0) gtot[wv] = s0;
    }
    __syncthreads();
    if (tid < 64){
      unsigned int x = (tid < 16) ? gtot[tid] : 0u;
      #pragma unroll
      for (int off = 1; off < 16; off <<= 1){
        unsigned int v = __shfl_down(x, off, 64);
        if (tid + off < 16) x += v;
      }
      if (tid < 16) Gsuf[tid] = x;
      if (tid == 16) Gsuf[16] = 0u;
    }
    __syncthreads();
    #pragma unroll
    for (int h = 0; h < 2; ++h){
      int d = tid + h*1024;
      unsigned int Sd  = bins[d] + Gsuf[(d >> 7) + 1];
      unsigned int Sd1 = (d < 2047) ? (bins[d+1] + Gsuf[((d+1) >> 7) + 1]) : 0u;
      if (Sd >= rem && Sd1 < rem){ scal[0] = rem - Sd1; scal[1] = (unsigned int)d; }
    }
    __syncthreads();
    rem = scal[0]; prefix |= scal[1] << shift;
    __syncthreads();
  }
  unsigned int T = prefix;
  unsigned int G = PRE_K - rem;   // # strictly greater than T; rem ties needed
  if (tid == 0){ scal[2] = 0; scal[3] = 0; }
  __syncthreads();
  // wave-aggregated scatter (slot order arbitrary; sort fixes final order)
  {
    unsigned long long below = (lane == 0) ? 0ull : ((~0ull) >> (64 - lane));
    for (unsigned int i = tid; i < n; i += 1024){
      unsigned long long pk = cd[i];
      unsigned int k32 = (unsigned int)(pk >> 32);
      bool gt = k32 > T, eq = k32 == T;
      unsigned long long bgt = __ballot(gt);
      if (bgt){
        int leader = (int)(__ffsll((long long)bgt) - 1);
        unsigned int base = 0;
        if (lane == leader) base = atomicAdd(&scal[2], (unsigned int)__popcll(bgt));
        base = (unsigned int)__shfl((int)base, leader, 64);
        if (gt){
          unsigned int s = base + (unsigned int)__popcll(bgt & below);  // s < G
          sel_l[s] = pk;
        }
      }
      unsigned long long beq = __ballot(eq);
      if (beq){
        int leader = (int)(__ffsll((long long)beq) - 1);
        unsigned int base = 0;
        if (lane == leader) base = atomicAdd(&scal[3], (unsigned int)__popcll(beq));
        base = (unsigned int)__shfl((int)base, leader, 64);
        if (eq){
          unsigned int e = base + (unsigned int)__popcll(beq & below);
          if (G + e < SORT_N) sel_l[G + e] = pk;
        }
      }
    }
  }
  __syncthreads();
  unsigned int ceq = scal[3];
  unsigned int tcap = SORT_N - G;
  unsigned int filled = G + ((ceq < tcap) ? ceq : tcap);
  for (unsigned int i = filled + tid; i < SORT_N; i += 1024) sel_l[i] = 0ull;
  __syncthreads();
  // bitonic sort 2048 descending: (key desc, idx asc) via ~idx packing
  for (int k = 2; k <= SORT_N; k <<= 1){
    for (int j = k >> 1; j > 0; j >>= 1){
      for (int i = tid; i < SORT_N; i += 1024){
        int ixj = i ^ j;
        if (ixj > i){
          bool up = ((i & k) == 0);
          unsigned long long x = sel_l[i], y = sel_l[ixj];
          if ((x < y) == up){ sel_l[i] = y; sel_l[ixj] = x; }
        }
      }
      __syncthreads();
    }
  }
  // decode + clip the exact top-2000 (score rebuilt bit-exactly from key)
  for (int k = tid; k < PRE_K; k += 1024){
    unsigned long long pk = sel_l[k];
    unsigned int key = (unsigned int)(pk >> 32);
    unsigned int idx = ~(unsigned int)(pk & 0xFFFFFFFFull);
    unsigned int ub = (key & 0x80000000u) ? (key ^ 0x80000000u) : (key ^ 0xFFFFFFFFu);
    float sc = __uint_as_float(ub);
    float4 a = ((const float4*)anchors)[idx];
    float4 d = ((const float4*)deltas)[(size_t)img*N_ANCH + idx];
    float w  = rn_add(rn_sub(a.z, a.x), 1.0f);
    float h  = rn_add(rn_sub(a.w, a.y), 1.0f);
    float cx = rn_add(a.x, rn_mul(0.5f, w));
    float cy = rn_add(a.y, rn_mul(0.5f, h));
    float dw = fminf(d.z, DCLIP);
    float dh = fminf(d.w, DCLIP);
    float pcx = rn_add(rn_mul(d.x, w), cx);
    float pcy = rn_add(rn_mul(d.y, h), cy);
    float pw = rn_mul((float)exp((double)dw), w);   // correctly-rounded f32 exp
    float ph = rn_mul((float)exp((double)dh), h);
    float x1 = rn_sub(pcx, rn_mul(0.5f, pw));
    float y1 = rn_sub(pcy, rn_mul(0.5f, ph));
    float x2 = rn_sub(rn_add(pcx, rn_mul(0.5f, pw)), 1.0f);
    float y2 = rn_sub(rn_add(pcy, rn_mul(0.5f, ph)), 1.0f);
    x1 = fminf(fmaxf(x1, 0.0f), IMG_W_M1);
    x2 = fminf(fmaxf(x2, 0.0f), IMG_W_M1);
    y1 = fminf(fmaxf(y1, 0.0f), IMG_H_M1);
    y2 = fminf(fmaxf(y2, 0.0f), IMG_H_M1);
    float bw = rn_add(rn_sub(x2, x1), 1.0f);
    float bh = rn_add(rn_sub(y2, y1), 1.0f);
    ((float4*)boxes)[(size_t)img*PRE_K + k] = make_float4(x1, y1, x2, y2);
    scores[img*PRE_K + k] = sc;
    areas[img*PRE_K + k]  = rn_mul(bw, bh);
    valid[img*PRE_K + k]  = (bw >= 0.0f && bh >= 0.0f) ? 1u : 0u;
  }
}

// ---------------- NMS suppression bitmask, BLOCK-TRANSPOSED: mtt[w][r][l] ----------------
// bit b of mtt[w][r][l] = "row r*64+b suppresses column w*64+l" (row < col).
__global__ void k_mask(const float* __restrict__ boxes, const float* __restrict__ areas,
                       unsigned long long* __restrict__ mtt){
  int w = blockIdx.x, r = blockIdx.y, img = blockIdx.z;
  if (w < r) return;
  __shared__ float4 rb[64];
  __shared__ float  ra[64];
  int ri = r*64 + threadIdx.x;
  if (ri < PRE_K){
    rb[threadIdx.x] = ((const float4*)boxes)[(size_t)img*PRE_K + ri];
    ra[threadIdx.x] = areas[img*PRE_K + ri];
  }
  __syncthreads();
  int j = w*64 + threadIdx.x;   // this thread's column
  unsigned long long bits = 0;
  if (j < PRE_K){
    float4 bj = ((const float4*)boxes)[(size_t)img*PRE_K + j];
    float aj = areas[img*PRE_K + j];
    int bmax = min(64, PRE_K - r*64);
    for (int b = 0; b < bmax; ++b){
      int row = r*64 + b;
      if (row >= j) continue;
      float4 br = rb[b];
      if (iou_gt(br.x,br.y,br.z,br.w,ra[b], bj.x,bj.y,bj.z,bj.w,aj)) bits |= 1ull << b;
    }
  }
  mtt[(size_t)img*(NMS_WORDS*NMS_WORDS*64) + ((size_t)w*NMS_WORDS + r)*64 + threadIdx.x] = bits;
}

// ---------------- greedy NMS reduce: Jacobi-fixpoint resolve + raw barriers ----------------
__global__ void __launch_bounds__(1024) k_nms_out(const unsigned long long* __restrict__ mtt,
                          const unsigned int* __restrict__ valid,
                          const float* __restrict__ boxes, const float* __restrict__ scores,
                          float* __restrict__ out){
  __shared__ unsigned long long keepw[NMS_WORDS];
  __shared__ unsigned int kpre[NMS_WORDS + 1];
  int img = blockIdx.x;
  int tid = threadIdx.x;
  int wv = tid >> 6, lane = tid & 63;
  const unsigned long long* M = mtt + (size_t)img * (NMS_WORDS * NMS_WORDS * 64);
  int wA = wv*2, wB = wv*2 + 1;

  int rA = wA*64 + lane, rB = wB*64 + lane;
  bool okA = (rA < PRE_K) && (valid[img*PRE_K + rA] != 0u);
  bool okB = (rB < PRE_K) && (valid[img*PRE_K + rB] != 0u);
  unsigned long long vA = __ballot(okA);
  unsigned long long vB = __ballot(okB);

  unsigned long long tdgA = M[((size_t)wA*NMS_WORDS + wA)*64 + lane];
  unsigned long long tdgB = M[((size_t)wB*NMS_WORDS + wB)*64 + lane];
  unsigned long long tX   = M[((size_t)wB*NMS_WORDS + wA)*64 + lane];

  bool deadA = false, deadB = false;

  unsigned long long a0=0, a1=0, b0=0, b1=0, n0=0, n1=0, n2=0, n3=0;
  if (wv > 0){
    a0 = M[((size_t)wA*NMS_WORDS + 0)*64 + lane];
    a1 = M[((size_t)wA*NMS_WORDS + 1)*64 + lane];
    b0 = M[((size_t)wB*NMS_WORDS + 0)*64 + lane];
    b1 = M[((size_t)wB*NMS_WORDS + 1)*64 + lane];
  }
  if (wv > 1){
    n0 = M[((size_t)wA*NMS_WORDS + 2)*64 + lane];
    n1 = M[((size_t)wA*NMS_WORDS + 3)*64 + lane];
    n2 = M[((size_t)wB*NMS_WORDS + 2)*64 + lane];
    n3 = M[((size_t)wB*NMS_WORDS + 3)*64 + lane];
  }

  for (int p = 0; p < NPAIR; ++p){
    if (wv == p){
      unsigned long long base = vA & ~__ballot(deadA);
      unsigned long long alive = base, prev;
      do {
        prev = alive;
        alive = base & ~__ballot((tdgA & prev) != 0ull);
      } while (alive != prev);
      unsigned long long kA = alive;
      unsigned long long supX = __ballot((tX & kA) != 0ull);
      unsigned long long baseB = vB & ~(__ballot(deadB) | supX);
      alive = baseB;
      do {
        prev = alive;
        alive = baseB & ~__ballot((tdgB & prev) != 0ull);
      } while (alive != prev);
      if (lane == 0){ keepw[wA] = kA; keepw[wB] = alive; }
    }
    __builtin_amdgcn_sched_barrier(0);
    asm volatile("s_waitcnt lgkmcnt(0)" ::: "memory");
    __builtin_amdgcn_s_barrier();
    __builtin_amdgcn_sched_barrier(0);
    if (wv > p){
      unsigned long long k0 = keepw[2*p], k1 = keepw[2*p+1];
      deadA = deadA || ((a0 & k0) != 0ull) || ((a1 & k1) != 0ull);
      deadB = deadB || ((b0 & k0) != 0ull) || ((b1 & k1) != 0ull);
      a0 = n0; a1 = n1; b0 = n2; b1 = n3;
      if (wv > p + 2){
        n0 = M[((size_t)wA*NMS_WORDS + (2*p+4))*64 + lane];
        n1 = M[((size_t)wA*NMS_WORDS + (2*p+5))*64 + lane];
        n2 = M[((size_t)wB*NMS_WORDS + (2*p+4))*64 + lane];
        n3 = M[((size_t)wB*NMS_WORDS + (2*p+5))*64 + lane];
      }
    }
  }

  __syncthreads();
  if (tid == 0){
    unsigned int s = 0;
    for (int ww = 0; ww < NMS_WORDS; ++ww){ kpre[ww] = s; s += __popcll(keepw[ww]); }
    kpre[NMS_WORDS] = s;
  }
  __syncthreads();
  unsigned int nkept = kpre[NMS_WORDS];
  for (int i = tid; i < PRE_K; i += blockDim.x){
    int ww = i >> 6, b = i & 63;
    unsigned long long kw = keepw[ww];
    bool kept = (kw >> b) & 1ull;
    unsigned long long below = (b == 0) ? 0ull : (kw & ((~0ull) >> (64 - b)));
    unsigned int rank = kpre[ww] + (unsigned int)__popcll(below);
    unsigned int pos = kept ? rank : (nkept + (unsigned int)i - rank);
    if (pos < POST_K){
      float4 bx = ((const float4*)boxes)[(size_t)img*PRE_K + i];
      float sc = kept ? scores[img*PRE_K + i] : -1e9f;
      float* o = out + ((size_t)img*POST_K + pos) * 5;
      o[0] = bx.x; o[1] = bx.y; o[2] = bx.z; o[3] = bx.w; o[4] = sc;
    }
  }
}

extern "C" void kernel_launch(void* const* d_in, const int* in_sizes, int n_in,
                              void* d_out, int out_size, void* d_ws, size_t ws_size,
                              hipStream_t stream) {
  const float* anchors    = (const float*)d_in[0];
  const float* objectness = (const float*)d_in[1];
  const float* deltas     = (const float*)d_in[2];
  float* out = (float*)d_out;
  char* ws = (char*)d_ws;

  unsigned int* state      = (unsigned int*)(ws + 0);        // 64 (bin[8] + rem[8])
  unsigned int* cnt        = (unsigned int*)(ws + 256);      // 2048 (256B/img)
  float* boxes             = (float*)(ws + 4096);            // 256000 (16B aligned)
  float* scores            = (float*)(ws + 260096);          // 64000
  float* areas             = (float*)(ws + 324096);          // 64000
  unsigned int* valid      = (unsigned int*)(ws + 388096);   // 64000
  // one 4 MB region reused sequentially (write->read fully ordered by stream):
  //   hsl  (hist slices, 8*64*2048*4 = 4 MB)   w:k_hist   r:k_scan
  //   cand (8*8192*8 = 512 KB)                 w:k_cand   r:k_selsort
  //   mtt  (block-transposed mask, 4 MB)       w:k_mask   r:k_nms_out
  unsigned int* hsl        = (unsigned int*)(ws + 458752);
  unsigned long long* cand = (unsigned long long*)(ws + 458752);
  unsigned long long* mtt  = (unsigned long long*)(ws + 458752);

  hipLaunchKernelGGL(k_hist, dim3(64, N_IMG), dim3(256), 0, stream, objectness, hsl);
  hipLaunchKernelGGL(k_scan, dim3(N_IMG), dim3(1024), 0, stream, hsl, state, cnt);
  hipLaunchKernelGGL(k_cand, dim3(64, N_IMG), dim3(256), 0, stream,
                     objectness, state, cnt, cand);
  hipLaunchKernelGGL(k_selsort, dim3(N_IMG), dim3(1024), 0, stream,
                     cand, cnt, state, anchors, deltas, boxes, scores, areas, valid);
  hipLaunchKernelGGL(k_mask, dim3(NMS_WORDS, NMS_WORDS, N_IMG), dim3(64), 0, stream,
                     boxes, areas, mtt);
  hipLaunchKernelGGL(k_nms_out, dim3(N_IMG), dim3(1024), 0, stream,
                     mtt, valid, boxes, scores, out);
}

// Round 15
// 119.518 us; speedup vs baseline: 1.1971x; 1.1490x over previous
//
#include <hip/hip_runtime.h>
#include <math.h>

#define N_IMG 8
#define N_ANCH 250000
#define PRE_K 2000
#define POST_K 1000
#define CAND_CAP 8192  // >= G + boundary-bin count (expected ~5.7K, ~39 sigma margin)
#define EQ_CAP 4096
#define NMS_WORDS 32   // ceil(2000/64)
#define NPAIR 16       // pairs of 64-row chunks
#define CNT_STRIDE 64  // uints per image: 256B -> private cacheline per image

#define IMG_W_M1 1332.0f
#define IMG_H_M1 799.0f
#define DCLIP 4.135166556742356f
#define NMS_T 0.7f

__device__ __forceinline__ float rn_add(float a, float b){ return __fadd_rn(a,b); }
__device__ __forceinline__ float rn_sub(float a, float b){ return __fsub_rn(a,b); }
__device__ __forceinline__ float rn_mul(float a, float b){ return __fmul_rn(a,b); }
__device__ __forceinline__ float rn_div(float a, float b){ return __fdiv_rn(a,b); }

// monotonic float->uint mapping (order-preserving, larger float -> larger uint)
__device__ __forceinline__ unsigned int mono_of(float f){
  unsigned int u = __float_as_uint(f);
  return u ^ ((u >> 31) ? 0xFFFFFFFFu : 0x80000000u);
}

// exact-op-order IoU > 0.7 test (mirrors reference float32 op sequence;
// fully symmetric in its two boxes: max/min/add/mul commutative)
__device__ __forceinline__ bool iou_gt(float x1,float y1,float x2,float y2,float a1,
                                       float X1,float Y1,float X2,float Y2,float a2){
  float ltx = fmaxf(x1, X1), lty = fmaxf(y1, Y1);
  float rbx = fminf(x2, X2), rby = fminf(y2, Y2);
  float wx = fmaxf(rn_add(rn_sub(rbx, ltx), 1.0f), 0.0f);
  float wy = fmaxf(rn_add(rn_sub(rby, lty), 1.0f), 0.0f);
  float inter = rn_mul(wx, wy);
  float iou = rn_div(inter, rn_sub(rn_add(a1, a2), inter));
  return iou > NMS_T;
}

// ---------------- histogram, PRIVATIZED: per-block slice, no atomics/init ----------------
__global__ void k_hist(const float* __restrict__ obj, unsigned int* __restrict__ hsl){
  __shared__ unsigned int lh[2048];
  int img = blockIdx.y;
  for (int i = threadIdx.x; i < 2048; i += blockDim.x) lh[i] = 0;
  __syncthreads();
  const float4* o4 = (const float4*)(obj + (size_t)img * N_ANCH);
  int stride = gridDim.x * blockDim.x;
  for (int i = blockIdx.x * blockDim.x + threadIdx.x; i < N_ANCH/4; i += stride){
    float4 v = o4[i];
    atomicAdd(&lh[mono_of(v.x) >> 21], 1u);
    atomicAdd(&lh[mono_of(v.y) >> 21], 1u);
    atomicAdd(&lh[mono_of(v.z) >> 21], 1u);
    atomicAdd(&lh[mono_of(v.w) >> 21], 1u);
  }
  __syncthreads();
  unsigned int* slice = hsl + ((size_t)img * 64 + blockIdx.x) * 2048;
  for (int i = threadIdx.x; i < 2048; i += blockDim.x) slice[i] = lh[i];
}

// ------- sum slices + suffix scan -> boundary bin AND rem0 (pass-0 result); zero cnt -------
__global__ void __launch_bounds__(1024) k_scan(const unsigned int* __restrict__ hsl,
                                               unsigned int* state, unsigned int* cnt){
  __shared__ unsigned int bins[2048];
  __shared__ unsigned int gtot[16];
  __shared__ unsigned int Gsuf[17];
  __shared__ unsigned int res[2];
  int img = blockIdx.x, tid = threadIdx.x;
  int wv = tid >> 6, lane = tid & 63;
  #pragma unroll
  for (int h = 0; h < 2; ++h){
    int bin = tid + h*1024;
    unsigned int acc = 0;
    #pragma unroll 8
    for (int s = 0; s < 64; ++s) acc += hsl[((size_t)img*64 + s)*2048 + bin];
    bins[bin] = acc;
  }
  __syncthreads();
  {
    unsigned int x0 = bins[wv*128 + lane];
    unsigned int x1 = bins[wv*128 + 64 + lane];
    unsigned int s1 = x1, s0 = x0, v;
    #pragma unroll
    for (int off = 1; off < 64; off <<= 1){
      v = __shfl_down(s1, off, 64); if (lane + off < 64) s1 += v;
      v = __shfl_down(s0, off, 64); if (lane + off < 64) s0 += v;
    }
    unsigned int T1 = __shfl(s1, 0, 64);
    s0 += T1;
    bins[wv*128 + lane] = s0;
    bins[wv*128 + 64 + lane] = s1;
    if (lane == 0) gtot[wv] = s0;
  }
  __syncthreads();
  if (tid < 64){
    unsigned int x = (tid < 16) ? gtot[tid] : 0u;
    #pragma unroll
    for (int off = 1; off < 16; off <<= 1){
      unsigned int v = __shfl_down(x, off, 64);
      if (tid + off < 16) x += v;
    }
    if (tid < 16) Gsuf[tid] = x;
    if (tid == 16) Gsuf[16] = 0u;
  }
  __syncthreads();
  #pragma unroll
  for (int h = 0; h < 2; ++h){
    int d = tid + h*1024;
    unsigned int Sd  = bins[d] + Gsuf[(d >> 7) + 1];
    unsigned int Sd1 = (d < 2047) ? (bins[d+1] + Gsuf[((d+1) >> 7) + 1]) : 0u;
    if (Sd >= PRE_K && Sd1 < PRE_K){ res[0] = (unsigned int)d; res[1] = PRE_K - Sd1; }
  }
  __syncthreads();
  if (tid == 0){ state[img] = res[0]; state[8 + img] = res[1]; }
  if (tid < CNT_STRIDE) cnt[img*CNT_STRIDE + tid] = 0;
}

// ---------------- collect candidates: top-11 bits >= boundary bin ----------------
__global__ void k_cand(const float* __restrict__ obj, const unsigned int* __restrict__ state,
                       unsigned int* cnt, unsigned long long* __restrict__ cand){
  int img = blockIdx.y;
  unsigned int bin = state[img];
  const float4* o4 = (const float4*)(obj + (size_t)img * N_ANCH);
  int stride = gridDim.x * blockDim.x;
  int lane = threadIdx.x & 63;
  unsigned long long below = (lane == 0) ? 0ull : ((~0ull) >> (64 - lane));
  for (int i = blockIdx.x * blockDim.x + threadIdx.x; i < N_ANCH/4; i += stride){
    float4 v = o4[i];
    #pragma unroll
    for (int s = 0; s < 4; ++s){
      float f = (s==0) ? v.x : (s==1) ? v.y : (s==2) ? v.z : v.w;
      unsigned int key = mono_of(f);
      bool hit = (key >> 21) >= bin;
      unsigned long long b = __ballot(hit);
      if (b){
        int leader = (int)(__ffsll((long long)b) - 1);
        unsigned int base = 0;
        if (lane == leader) base = atomicAdd(&cnt[img*CNT_STRIDE], (unsigned int)__popcll(b));
        base = (unsigned int)__shfl((int)base, leader, 64);
        if (hit){
          unsigned int slot = base + (unsigned int)__popcll(b & below);
          if (slot < CAND_CAP)
            cand[(size_t)img*CAND_CAP + slot] =
              ((unsigned long long)key << 32) | (unsigned long long)(~(unsigned int)(i*4 + s));
        }
      }
    }
  }
}

// ---------------- per-image: radix passes 1-2 + tie rule -> selset (UNORDERED set) --------
// Round-14 lesson: the 66-stage bitonic (66 barriers x 16 waves on 8 CUs) was
// the bulk of k_selsort. Packed keys (key<<32)|~idx are UNIQUE, so the final
// position is just rank = #{pk' > pk} -- computed massively parallel in
// k_rankdec. This kernel only determines the exact SET of 2000.
__global__ void __launch_bounds__(1024) k_select(
    const unsigned long long* __restrict__ cand, const unsigned int* __restrict__ cnt,
    const unsigned int* __restrict__ state, unsigned long long* __restrict__ selset){
  __shared__ unsigned int bins[2048];           // 8 KB
  __shared__ unsigned int scal[4];              // rem, bin, cgt, ceq
  __shared__ unsigned int gtot[16];
  __shared__ unsigned int Gsuf[17];
  __shared__ unsigned int eqidx[EQ_CAP];        // 16 KB tie idx list
  int img = blockIdx.x, tid = threadIdx.x;
  int wv = tid >> 6, lane = tid & 63;
  unsigned int n = cnt[img*CNT_STRIDE]; if (n > CAND_CAP) n = CAND_CAP;
  const unsigned long long* cd = cand + (size_t)img*CAND_CAP;

  unsigned int rem = state[8 + img];
  unsigned int prefix = state[img] << 21;
  #pragma unroll
  for (int p = 1; p < 3; ++p){
    int shift  = (p==1) ? 10 : 0;
    int mshift = (p==1) ? 21 : 10;
    unsigned int bmask = (p==2) ? 1023u : 2047u;
    bins[tid] = 0; bins[tid+1024] = 0;
    __syncthreads();
    for (unsigned int i = tid; i < n; i += 1024){
      unsigned int k32 = (unsigned int)(cd[i] >> 32);
      if ((k32 >> mshift) == (prefix >> mshift))
        atomicAdd(&bins[(k32 >> shift) & bmask], 1u);
    }
    __syncthreads();
    {
      unsigned int x0 = bins[wv*128 + lane];
      unsigned int x1 = bins[wv*128 + 64 + lane];
      unsigned int s1 = x1, s0 = x0, v;
      #pragma unroll
      for (int off = 1; off < 64; off <<= 1){
        v = __shfl_down(s1, off, 64); if (lane + off < 64) s1 += v;
        v = __shfl_down(s0, off, 64); if (lane + off < 64) s0 += v;
      }
      unsigned int T1 = __shfl(s1, 0, 64);
      s0 += T1;
      bins[wv*128 + lane] = s0;
      bins[wv*128 + 64 + lane] = s1;
      if (lane == 0) gtot[wv] = s0;
    }
    __syncthreads();
    if (tid < 64){
      unsigned int x = (tid < 16) ? gtot[tid] : 0u;
      #pragma unroll
      for (int off = 1; off < 16; off <<= 1){
        unsigned int v = __shfl_down(x, off, 64);
        if (tid + off < 16) x += v;
      }
      if (tid < 16) Gsuf[tid] = x;
      if (tid == 16) Gsuf[16] = 0u;
    }
    __syncthreads();
    #pragma unroll
    for (int h = 0; h < 2; ++h){
      int d = tid + h*1024;
      unsigned int Sd  = bins[d] + Gsuf[(d >> 7) + 1];
      unsigned int Sd1 = (d < 2047) ? (bins[d+1] + Gsuf[((d+1) >> 7) + 1]) : 0u;
      if (Sd >= rem && Sd1 < rem){ scal[0] = rem - Sd1; scal[1] = (unsigned int)d; }
    }
    __syncthreads();
    rem = scal[0]; prefix |= scal[1] << shift;
    __syncthreads();
  }
  unsigned int T = prefix;
  unsigned int G = PRE_K - rem;   // exactly G keys > T; rem ties needed
  if (tid == 0){ scal[2] = 0; scal[3] = 0; }
  __syncthreads();
  // wave-aggregated scatter: gt -> selset slots [0,G); eq idx -> eqidx list
  {
    unsigned long long below = (lane == 0) ? 0ull : ((~0ull) >> (64 - lane));
    unsigned long long* ss = selset + (size_t)img * 2048;
    for (unsigned int i = tid; i < n; i += 1024){
      unsigned long long pk = cd[i];
      unsigned int k32 = (unsigned int)(pk >> 32);
      bool gt = k32 > T, eq = k32 == T;
      unsigned long long bgt = __ballot(gt);
      if (bgt){
        int leader = (int)(__ffsll((long long)bgt) - 1);
        unsigned int base = 0;
        if (lane == leader) base = atomicAdd(&scal[2], (unsigned int)__popcll(bgt));
        base = (unsigned int)__shfl((int)base, leader, 64);
        if (gt){
          unsigned int s = base + (unsigned int)__popcll(bgt & below);  // s < G
          ss[s] = pk;
        }
      }
      unsigned long long beq = __ballot(eq);
      if (beq){
        int leader = (int)(__ffsll((long long)beq) - 1);
        unsigned int base = 0;
        if (lane == leader) base = atomicAdd(&scal[3], (unsigned int)__popcll(beq));
        base = (unsigned int)__shfl((int)base, leader, 64);
        if (eq){
          unsigned int e = base + (unsigned int)__popcll(beq & below);
          if (e < EQ_CAP) eqidx[e] = ~(unsigned int)(pk & 0xFFFFFFFFull);  // raw idx
        }
      }
    }
  }
  __syncthreads();
  // ties: take the rem smallest idxs (idx-rank among eq set), slots G+r
  unsigned int ceq = scal[3]; if (ceq > EQ_CAP) ceq = EQ_CAP;
  for (unsigned int t = tid; t < ceq; t += 1024){
    unsigned int my = eqidx[t];
    unsigned int r = 0;
    for (unsigned int i = 0; i < ceq; ++i) r += (eqidx[i] < my) ? 1u : 0u;
    if (r < rem)
      selset[(size_t)img*2048 + G + r] =
        ((unsigned long long)T << 32) | (unsigned long long)(~my);
  }
}

// ---------------- parallel rank + decode: 4 threads/element, 256 blocks ----------------
// rank = #{pk' > pk} over the 2000 unique packed keys == exact position in
// (score desc, idx asc) order. LDS reads are wave-uniform (broadcast).
__global__ void __launch_bounds__(256) k_rankdec(
    const unsigned long long* __restrict__ selset,
    const float* __restrict__ anchors, const float* __restrict__ deltas,
    float* __restrict__ boxes, float* __restrict__ scores,
    float* __restrict__ areas, unsigned int* __restrict__ valid){
  __shared__ unsigned long long ls[PRE_K];     // 16 KB
  __shared__ unsigned int part[4][64];
  int img = blockIdx.y, tid = threadIdx.x;
  int wv = tid >> 6, lane = tid & 63;
  const unsigned long long* ss = selset + (size_t)img * 2048;
  for (int i = tid; i < PRE_K; i += 256) ls[i] = ss[i];
  __syncthreads();
  int e = blockIdx.x * 64 + lane;              // element this lane ranks
  bool live = (e < PRE_K);
  unsigned long long mine = live ? ls[e] : 0ull;
  unsigned int r = 0;
  int s0 = wv * 500, s1 = s0 + 500;            // 4 disjoint segments cover 2000
  #pragma unroll 4
  for (int i = s0; i < s1; ++i) r += (ls[i] > mine) ? 1u : 0u;
  part[wv][lane] = r;
  __syncthreads();
  if (wv == 0 && live){
    unsigned int rank = part[0][lane] + part[1][lane] + part[2][lane] + part[3][lane];
    unsigned long long pk = mine;
    unsigned int key = (unsigned int)(pk >> 32);
    unsigned int idx = ~(unsigned int)(pk & 0xFFFFFFFFull);
    unsigned int ub = (key & 0x80000000u) ? (key ^ 0x80000000u) : (key ^ 0xFFFFFFFFu);
    float sc = __uint_as_float(ub);
    float4 a = ((const float4*)anchors)[idx];
    float4 d = ((const float4*)deltas)[(size_t)img*N_ANCH + idx];
    float w  = rn_add(rn_sub(a.z, a.x), 1.0f);
    float h  = rn_add(rn_sub(a.w, a.y), 1.0f);
    float cx = rn_add(a.x, rn_mul(0.5f, w));
    float cy = rn_add(a.y, rn_mul(0.5f, h));
    float dw = fminf(d.z, DCLIP);
    float dh = fminf(d.w, DCLIP);
    float pcx = rn_add(rn_mul(d.x, w), cx);
    float pcy = rn_add(rn_mul(d.y, h), cy);
    float pw = rn_mul((float)exp((double)dw), w);   // correctly-rounded f32 exp
    float ph = rn_mul((float)exp((double)dh), h);
    float x1 = rn_sub(pcx, rn_mul(0.5f, pw));
    float y1 = rn_sub(pcy, rn_mul(0.5f, ph));
    float x2 = rn_sub(rn_add(pcx, rn_mul(0.5f, pw)), 1.0f);
    float y2 = rn_sub(rn_add(pcy, rn_mul(0.5f, ph)), 1.0f);
    x1 = fminf(fmaxf(x1, 0.0f), IMG_W_M1);
    x2 = fminf(fmaxf(x2, 0.0f), IMG_W_M1);
    y1 = fminf(fmaxf(y1, 0.0f), IMG_H_M1);
    y2 = fminf(fmaxf(y2, 0.0f), IMG_H_M1);
    float bw = rn_add(rn_sub(x2, x1), 1.0f);
    float bh = rn_add(rn_sub(y2, y1), 1.0f);
    ((float4*)boxes)[(size_t)img*PRE_K + rank] = make_float4(x1, y1, x2, y2);
    scores[img*PRE_K + rank] = sc;
    areas[img*PRE_K + rank]  = rn_mul(bw, bh);
    valid[img*PRE_K + rank]  = (bw >= 0.0f && bh >= 0.0f) ? 1u : 0u;
  }
}

// ---------------- NMS suppression bitmask, BLOCK-TRANSPOSED: mtt[w][r][l] ----------------
__global__ void k_mask(const float* __restrict__ boxes, const float* __restrict__ areas,
                       unsigned long long* __restrict__ mtt){
  int w = blockIdx.x, r = blockIdx.y, img = blockIdx.z;
  if (w < r) return;
  __shared__ float4 rb[64];
  __shared__ float  ra[64];
  int ri = r*64 + threadIdx.x;
  if (ri < PRE_K){
    rb[threadIdx.x] = ((const float4*)boxes)[(size_t)img*PRE_K + ri];
    ra[threadIdx.x] = areas[img*PRE_K + ri];
  }
  __syncthreads();
  int j = w*64 + threadIdx.x;   // this thread's column
  unsigned long long bits = 0;
  if (j < PRE_K){
    float4 bj = ((const float4*)boxes)[(size_t)img*PRE_K + j];
    float aj = areas[img*PRE_K + j];
    int bmax = min(64, PRE_K - r*64);
    for (int b = 0; b < bmax; ++b){
      int row = r*64 + b;
      if (row >= j) continue;
      float4 br = rb[b];
      if (iou_gt(br.x,br.y,br.z,br.w,ra[b], bj.x,bj.y,bj.z,bj.w,aj)) bits |= 1ull << b;
    }
  }
  mtt[(size_t)img*(NMS_WORDS*NMS_WORDS*64) + ((size_t)w*NMS_WORDS + r)*64 + threadIdx.x] = bits;
}

// ---------------- greedy NMS reduce: Jacobi-fixpoint resolve + raw barriers ----------------
__global__ void __launch_bounds__(1024) k_nms_out(const unsigned long long* __restrict__ mtt,
                          const unsigned int* __restrict__ valid,
                          const float* __restrict__ boxes, const float* __restrict__ scores,
                          float* __restrict__ out){
  __shared__ unsigned long long keepw[NMS_WORDS];
  __shared__ unsigned int kpre[NMS_WORDS + 1];
  int img = blockIdx.x;
  int tid = threadIdx.x;
  int wv = tid >> 6, lane = tid & 63;
  const unsigned long long* M = mtt + (size_t)img * (NMS_WORDS * NMS_WORDS * 64);
  int wA = wv*2, wB = wv*2 + 1;

  int rA = wA*64 + lane, rB = wB*64 + lane;
  bool okA = (rA < PRE_K) && (valid[img*PRE_K + rA] != 0u);
  bool okB = (rB < PRE_K) && (valid[img*PRE_K + rB] != 0u);
  unsigned long long vA = __ballot(okA);
  unsigned long long vB = __ballot(okB);

  unsigned long long tdgA = M[((size_t)wA*NMS_WORDS + wA)*64 + lane];
  unsigned long long tdgB = M[((size_t)wB*NMS_WORDS + wB)*64 + lane];
  unsigned long long tX   = M[((size_t)wB*NMS_WORDS + wA)*64 + lane];

  bool deadA = false, deadB = false;

  unsigned long long a0=0, a1=0, b0=0, b1=0, n0=0, n1=0, n2=0, n3=0;
  if (wv > 0){
    a0 = M[((size_t)wA*NMS_WORDS + 0)*64 + lane];
    a1 = M[((size_t)wA*NMS_WORDS + 1)*64 + lane];
    b0 = M[((size_t)wB*NMS_WORDS + 0)*64 + lane];
    b1 = M[((size_t)wB*NMS_WORDS + 1)*64 + lane];
  }
  if (wv > 1){
    n0 = M[((size_t)wA*NMS_WORDS + 2)*64 + lane];
    n1 = M[((size_t)wA*NMS_WORDS + 3)*64 + lane];
    n2 = M[((size_t)wB*NMS_WORDS + 2)*64 + lane];
    n3 = M[((size_t)wB*NMS_WORDS + 3)*64 + lane];
  }

  for (int p = 0; p < NPAIR; ++p){
    if (wv == p){
      unsigned long long base = vA & ~__ballot(deadA);
      unsigned long long alive = base, prev;
      do {
        prev = alive;
        alive = base & ~__ballot((tdgA & prev) != 0ull);
      } while (alive != prev);
      unsigned long long kA = alive;
      unsigned long long supX = __ballot((tX & kA) != 0ull);
      unsigned long long baseB = vB & ~(__ballot(deadB) | supX);
      alive = baseB;
      do {
        prev = alive;
        alive = baseB & ~__ballot((tdgB & prev) != 0ull);
      } while (alive != prev);
      if (lane == 0){ keepw[wA] = kA; keepw[wB] = alive; }
    }
    __builtin_amdgcn_sched_barrier(0);
    asm volatile("s_waitcnt lgkmcnt(0)" ::: "memory");
    __builtin_amdgcn_s_barrier();
    __builtin_amdgcn_sched_barrier(0);
    if (wv > p){
      unsigned long long k0 = keepw[2*p], k1 = keepw[2*p+1];
      deadA = deadA || ((a0 & k0) != 0ull) || ((a1 & k1) != 0ull);
      deadB = deadB || ((b0 & k0) != 0ull) || ((b1 & k1) != 0ull);
      a0 = n0; a1 = n1; b0 = n2; b1 = n3;
      if (wv > p + 2){
        n0 = M[((size_t)wA*NMS_WORDS + (2*p+4))*64 + lane];
        n1 = M[((size_t)wA*NMS_WORDS + (2*p+5))*64 + lane];
        n2 = M[((size_t)wB*NMS_WORDS + (2*p+4))*64 + lane];
        n3 = M[((size_t)wB*NMS_WORDS + (2*p+5))*64 + lane];
      }
    }
  }

  __syncthreads();
  if (tid == 0){
    unsigned int s = 0;
    for (int ww = 0; ww < NMS_WORDS; ++ww){ kpre[ww] = s; s += __popcll(keepw[ww]); }
    kpre[NMS_WORDS] = s;
  }
  __syncthreads();
  unsigned int nkept = kpre[NMS_WORDS];
  for (int i = tid; i < PRE_K; i += blockDim.x){
    int ww = i >> 6, b = i & 63;
    unsigned long long kw = keepw[ww];
    bool kept = (kw >> b) & 1ull;
    unsigned long long below = (b == 0) ? 0ull : (kw & ((~0ull) >> (64 - b)));
    unsigned int rank = kpre[ww] + (unsigned int)__popcll(below);
    unsigned int pos = kept ? rank : (nkept + (unsigned int)i - rank);
    if (pos < POST_K){
      float4 bx = ((const float4*)boxes)[(size_t)img*PRE_K + i];
      float sc = kept ? scores[img*PRE_K + i] : -1e9f;
      float* o = out + ((size_t)img*POST_K + pos) * 5;
      o[0] = bx.x; o[1] = bx.y; o[2] = bx.z; o[3] = bx.w; o[4] = sc;
    }
  }
}

extern "C" void kernel_launch(void* const* d_in, const int* in_sizes, int n_in,
                              void* d_out, int out_size, void* d_ws, size_t ws_size,
                              hipStream_t stream) {
  const float* anchors    = (const float*)d_in[0];
  const float* objectness = (const float*)d_in[1];
  const float* deltas     = (const float*)d_in[2];
  float* out = (float*)d_out;
  char* ws = (char*)d_ws;

  unsigned int* state      = (unsigned int*)(ws + 0);        // 64 (bin[8] + rem[8])
  unsigned int* cnt        = (unsigned int*)(ws + 256);      // 2048 (256B/img)
  float* boxes             = (float*)(ws + 4096);            // 256000 (16B aligned)
  float* scores            = (float*)(ws + 260096);          // 64000
  float* areas             = (float*)(ws + 324096);          // 64000
  unsigned int* valid      = (unsigned int*)(ws + 388096);   // 64000
  // one 4 MB region reused sequentially (write->read fully ordered by stream):
  //   hsl  (hist slices, 8*64*2048*4 = 4 MB)   w:k_hist   r:k_scan
  //   cand (8*8192*8 = 512 KB)                 w:k_cand   r:k_select
  //   mtt  (block-transposed mask, 4 MB)       w:k_mask   r:k_nms_out
  unsigned int* hsl        = (unsigned int*)(ws + 458752);
  unsigned long long* cand = (unsigned long long*)(ws + 458752);
  unsigned long long* mtt  = (unsigned long long*)(ws + 458752);
  // selset AFTER the 4 MB region (alive across k_select -> k_rankdec while
  // cand region is reused): 8*2048*8 = 128 KB; max ws use 4,784,128 B.
  unsigned long long* selset = (unsigned long long*)(ws + 4653056);

  hipLaunchKernelGGL(k_hist, dim3(64, N_IMG), dim3(256), 0, stream, objectness, hsl);
  hipLaunchKernelGGL(k_scan, dim3(N_IMG), dim3(1024), 0, stream, hsl, state, cnt);
  hipLaunchKernelGGL(k_cand, dim3(64, N_IMG), dim3(256), 0, stream,
                     objectness, state, cnt, cand);
  hipLaunchKernelGGL(k_select, dim3(N_IMG), dim3(1024), 0, stream,
                     cand, cnt, state, selset);
  hipLaunchKernelGGL(k_rankdec, dim3(32, N_IMG), dim3(256), 0, stream,
                     selset, anchors, deltas, boxes, scores, areas, valid);
  hipLaunchKernelGGL(k_mask, dim3(NMS_WORDS, NMS_WORDS, N_IMG), dim3(64), 0, stream,
                     boxes, areas, mtt);
  hipLaunchKernelGGL(k_nms_out, dim3(N_IMG), dim3(1024), 0, stream,
                     mtt, valid, boxes, scores, out);
}